// Round 1
// baseline (9529.214 us; speedup 1.0000x reference)
//
#include <hip/hip_runtime.h>
#include <hip/hip_fp16.h>
#include <stdint.h>

typedef _Float16 f16;
typedef __attribute__((ext_vector_type(8))) _Float16 f16x8;
typedef __attribute__((ext_vector_type(4))) float f32x4;

// fp32 -> (hi, lo*2^11) fp16 split (Markidis).  a ~= hi + lo/2048.
__device__ __forceinline__ void splitf(float v, f16& h, f16& l) {
  f16 hh = (f16)v;
  h = hh;
  l = (f16)((v - (float)hh) * 2048.0f);
}

// ---------------------------------------------------------------- x concat+split
__global__ void k_split_x(const float* __restrict__ words, const float* __restrict__ ctx,
                          f16* __restrict__ xh, f16* __restrict__ xl) {
  int idx = blockIdx.x * 256 + threadIdx.x;   // 256*4096 elements
  int c = idx & 4095;
  int r = idx >> 12;
  float v = (c < 2048) ? words[r * 2048 + c] : ctx[r * 2048 + (c - 2048)];
  f16 h, l; splitf(v, h, l);
  xh[idx] = h; xl[idx] = l;
}

// ---------------------------------------------------------------- split-fp16 GEMM
// C(M x Nn) = A(M x K) * B(K x Nn) + bias, A pre-split f16 hi/lo, B fp32 converted
// on the fly.  Tiles: BM=128, BN=64, BK=32.  4 waves (2x2), wave tile 64x32.
// LDS B layout: [g=k/8][n (pad 65)][j=k%8] so B-frags are contiguous ds_read_b128.
template<bool ELU>
__global__ __launch_bounds__(256)
void k_gemm_split(const f16* __restrict__ Ah, const f16* __restrict__ Al,
                  const float* __restrict__ B, const float* __restrict__ bias,
                  f16* __restrict__ Ch, f16* __restrict__ Cl,
                  int M, int Nn, int K) {
  __shared__ f16 sA[2][2][128 * 32];
  __shared__ f16 sB[2][2][4 * 65 * 8];
  const int tid = threadIdx.x;
  const int m0 = blockIdx.y * 128;
  const int n0 = blockIdx.x * 64;
  const int wid = tid >> 6, lane = tid & 63;
  const int wm = (wid >> 1) * 64, wn = (wid & 1) * 32;
  const int lx = lane & 15, lg = lane >> 4;

  f32x4 zero = {0.f, 0.f, 0.f, 0.f};
  f32x4 acc_h[4][2], acc_x[4][2];
#pragma unroll
  for (int i = 0; i < 4; ++i)
#pragma unroll
    for (int j = 0; j < 2; ++j) { acc_h[i][j] = zero; acc_x[i][j] = zero; }

  const int NT = K >> 5;

  auto stage = [&](int ktile, int bufi) {
    // A: 128 rows x 32 k (hi & lo): thread -> (row, 16-elem half)
    int row = tid >> 1, half = tid & 1;
    size_t gof = (size_t)(m0 + row) * K + (size_t)ktile * 32 + half * 16;
    int lof = row * 32 + half * 16;
    *(f16x8*)&sA[bufi][0][lof]     = *(const f16x8*)(Ah + gof);
    *(f16x8*)&sA[bufi][0][lof + 8] = *(const f16x8*)(Ah + gof + 8);
    *(f16x8*)&sA[bufi][1][lof]     = *(const f16x8*)(Al + gof);
    *(f16x8*)&sA[bufi][1][lof + 8] = *(const f16x8*)(Al + gof + 8);
    // B: 32 k-rows x 64 n fp32, convert+split, write octet layout
    int kk = tid >> 3, nb = (tid & 7) * 8;
    const float* gp = B + (size_t)((size_t)ktile * 32 + kk) * Nn + n0 + nb;
    float4 v0 = *(const float4*)gp;
    float4 v1 = *(const float4*)(gp + 4);
    float vv[8] = {v0.x, v0.y, v0.z, v0.w, v1.x, v1.y, v1.z, v1.w};
    int gi = kk >> 3, jj = kk & 7;
#pragma unroll
    for (int q = 0; q < 8; ++q) {
      f16 hh, ll; splitf(vv[q], hh, ll);
      sB[bufi][0][gi * 520 + (nb + q) * 8 + jj] = hh;
      sB[bufi][1][gi * 520 + (nb + q) * 8 + jj] = ll;
    }
  };

  stage(0, 0);
  int buf = 0;
  for (int kt = 0; kt < NT; ++kt) {
    __syncthreads();
    if (kt + 1 < NT) stage(kt + 1, buf ^ 1);
    f16x8 a_h[4], a_l[4], b_h[2], b_l[2];
#pragma unroll
    for (int mi = 0; mi < 4; ++mi) {
      int row = wm + mi * 16 + lx;
      a_h[mi] = *(const f16x8*)&sA[buf][0][row * 32 + lg * 8];
      a_l[mi] = *(const f16x8*)&sA[buf][1][row * 32 + lg * 8];
    }
#pragma unroll
    for (int ni = 0; ni < 2; ++ni) {
      int col = wn + ni * 16 + lx;
      b_h[ni] = *(const f16x8*)&sB[buf][0][lg * 520 + col * 8];
      b_l[ni] = *(const f16x8*)&sB[buf][1][lg * 520 + col * 8];
    }
#pragma unroll
    for (int mi = 0; mi < 4; ++mi)
#pragma unroll
      for (int ni = 0; ni < 2; ++ni) {
        acc_h[mi][ni] = __builtin_amdgcn_mfma_f32_16x16x32_f16(a_h[mi], b_h[ni], acc_h[mi][ni], 0, 0, 0);
        acc_x[mi][ni] = __builtin_amdgcn_mfma_f32_16x16x32_f16(a_h[mi], b_l[ni], acc_x[mi][ni], 0, 0, 0);
        acc_x[mi][ni] = __builtin_amdgcn_mfma_f32_16x16x32_f16(a_l[mi], b_h[ni], acc_x[mi][ni], 0, 0, 0);
      }
    buf ^= 1;
  }
#pragma unroll
  for (int mi = 0; mi < 4; ++mi)
#pragma unroll
    for (int ni = 0; ni < 2; ++ni) {
      int col = n0 + wn + ni * 16 + lx;
      float bs = bias[col];
#pragma unroll
      for (int r = 0; r < 4; ++r) {
        int row = m0 + wm + mi * 16 + lg * 4 + r;
        float c = acc_h[mi][ni][r] + acc_x[mi][ni][r] * (1.0f / 2048.0f) + bs;
        if (ELU) c = (c > 0.0f) ? c : expm1f(c);
        f16 hh, ll; splitf(c, hh, ll);
        size_t o = (size_t)row * Nn + col;
        Ch[o] = hh; Cl[o] = ll;
      }
    }
}

// ---------------------------------------------------------------- K = E E^T
__global__ __launch_bounds__(256)
void k_kgemm(const f16* __restrict__ Eh, const f16* __restrict__ El, float* __restrict__ Kout) {
  const int tid = threadIdx.x;
  const int wid = tid >> 6, lane = tid & 63;
  const int m0 = blockIdx.y * 64 + (wid >> 1) * 32;
  const int n0 = blockIdx.x * 64 + (wid & 1) * 32;
  const int lx = lane & 15, lg = lane >> 4;
  f32x4 zero = {0.f, 0.f, 0.f, 0.f};
  f32x4 acc_h[2][2], acc_x[2][2];
#pragma unroll
  for (int i = 0; i < 2; ++i)
#pragma unroll
    for (int j = 0; j < 2; ++j) { acc_h[i][j] = zero; acc_x[i][j] = zero; }
  for (int kt = 0; kt < 128; ++kt) {
    f16x8 ah[2], al[2], bh[2], bl[2];
#pragma unroll
    for (int mi = 0; mi < 2; ++mi) {
      size_t o = (size_t)(m0 + mi * 16 + lx) * 4096 + kt * 32 + lg * 8;
      ah[mi] = *(const f16x8*)(Eh + o);
      al[mi] = *(const f16x8*)(El + o);
    }
#pragma unroll
    for (int ni = 0; ni < 2; ++ni) {
      size_t o = (size_t)(n0 + ni * 16 + lx) * 4096 + kt * 32 + lg * 8;
      bh[ni] = *(const f16x8*)(Eh + o);
      bl[ni] = *(const f16x8*)(El + o);
    }
#pragma unroll
    for (int mi = 0; mi < 2; ++mi)
#pragma unroll
      for (int ni = 0; ni < 2; ++ni) {
        acc_h[mi][ni] = __builtin_amdgcn_mfma_f32_16x16x32_f16(ah[mi], bh[ni], acc_h[mi][ni], 0, 0, 0);
        acc_x[mi][ni] = __builtin_amdgcn_mfma_f32_16x16x32_f16(ah[mi], bl[ni], acc_x[mi][ni], 0, 0, 0);
        acc_x[mi][ni] = __builtin_amdgcn_mfma_f32_16x16x32_f16(al[mi], bh[ni], acc_x[mi][ni], 0, 0, 0);
      }
  }
#pragma unroll
  for (int mi = 0; mi < 2; ++mi)
#pragma unroll
    for (int ni = 0; ni < 2; ++ni)
#pragma unroll
      for (int r = 0; r < 4; ++r)
        Kout[(m0 + mi * 16 + lg * 4 + r) * 256 + n0 + ni * 16 + lx] =
            acc_h[mi][ni][r] + acc_x[mi][ni][r] * (1.0f / 2048.0f);
}

// ---------------------------------------------------------------- Householder tridiagonalization
// Packed lower triangle in LDS (131KB).  1 workgroup, 1024 threads.
__global__ __launch_bounds__(1024)
void k_tridiag(const float* __restrict__ Kin, float* __restrict__ dia,
               float* __restrict__ off, float* __restrict__ refl, float* __restrict__ tau) {
  extern __shared__ float lds[];
  float* A   = lds;            // 32896 floats packed lower triangle
  float* vv  = lds + 32896;    // 256
  float* ww  = vv + 256;       // 256
  float* uu  = ww + 256;       // 256
  float* red = uu + 256;       // 16
  float* scal = red + 16;      // 4
  const int tid = threadIdx.x;
  const int lane = tid & 63, wid = tid >> 6;

  for (int j = tid >> 2; j < 256; j += 256) {
    int base = (j * (j + 1)) >> 1;
    for (int kq = (tid & 3); kq <= j; kq += 4) A[base + kq] = Kin[j * 256 + kq];
  }
  __syncthreads();

  for (int i = 0; i < 254; ++i) {
    const int lo = i + 1;
    for (int j = lo + tid; j < 256; j += 1024) vv[j] = A[((j * (j + 1)) >> 1) + i];
    __syncthreads();
    float ps = 0.0f;
    for (int j = lo + 1 + tid; j < 256; j += 1024) { float x = vv[j]; ps += x * x; }
    for (int m = 32; m; m >>= 1) ps += __shfl_xor(ps, m);
    if (lane == 0) red[wid] = ps;
    __syncthreads();
    if (tid == 0) {
      float sig = 0.0f;
      for (int wq = 0; wq < 16; ++wq) sig += red[wq];
      float alpha = vv[lo];
      float tv, inv, beta;
      if (sig <= 1e-35f) { beta = alpha; tv = 0.0f; inv = 0.0f; }
      else {
        float mu = sqrtf(alpha * alpha + sig);
        beta = (alpha > 0.0f) ? -mu : mu;
        tv = (beta - alpha) / beta;
        inv = 1.0f / (alpha - beta);
      }
      scal[0] = tv; scal[1] = inv;
      dia[i] = A[((i * (i + 1)) >> 1) + i];
      off[i] = beta;
      tau[i] = tv;
    }
    __syncthreads();
    const float tv = scal[0], inv = scal[1];
    for (int j = lo + tid; j < 256; j += 1024) {
      float v = (j == lo) ? ((tv != 0.0f) ? 1.0f : 0.0f) : vv[j] * inv;
      vv[j] = v;
      refl[i * 256 + j] = v;
    }
    __syncthreads();
    // w = A*v : row pass (k<=j incl diag) then column pass (j>k)
    for (int j = lo + wid; j < 256; j += 16) {
      const float* Ar = A + ((j * (j + 1)) >> 1);
      float s = 0.0f;
      for (int kq = lo + lane; kq <= j; kq += 64) s += Ar[kq] * vv[kq];
      for (int m = 32; m; m >>= 1) s += __shfl_xor(s, m);
      if (lane == 0) ww[j] = s;
    }
    __syncthreads();
    for (int kq = lo + wid; kq < 256; kq += 16) {
      float s = 0.0f;
      for (int j = kq + 1 + lane; j < 256; j += 64) s += A[((j * (j + 1)) >> 1) + kq] * vv[j];
      for (int m = 32; m; m >>= 1) s += __shfl_xor(s, m);
      if (lane == 0) ww[kq] += s;
    }
    __syncthreads();
    float pp = 0.0f;
    for (int j = lo + tid; j < 256; j += 1024) pp += vv[j] * ww[j];
    for (int m = 32; m; m >>= 1) pp += __shfl_xor(pp, m);
    if (lane == 0) red[wid] = pp;
    __syncthreads();
    if (tid == 0) {
      float pw = 0.0f;
      for (int wq = 0; wq < 16; ++wq) pw += red[wq];
      scal[2] = pw;
    }
    __syncthreads();
    const float hc = 0.5f * tv * tv * scal[2];
    for (int j = lo + tid; j < 256; j += 1024) uu[j] = tv * ww[j] - hc * vv[j];
    __syncthreads();
    for (int j = lo + wid; j < 256; j += 16) {
      float vj = vv[j], uj = uu[j];
      float* Ar = A + ((j * (j + 1)) >> 1);
      for (int kq = lo + lane; kq <= j; kq += 64) Ar[kq] -= vj * uu[kq] + uj * vv[kq];
    }
    __syncthreads();
  }
  if (tid == 0) {
    dia[254] = A[((254 * 255) >> 1) + 254];
    dia[255] = A[((255 * 256) >> 1) + 255];
    off[254] = A[((255 * 256) >> 1) + 254];
    off[255] = 0.0f;
    tau[254] = 0.0f; tau[255] = 0.0f;
  }
}

// ---------------------------------------------------------------- bisection eigenvalues + keep
__global__ __launch_bounds__(256)
void k_bisect(const float* __restrict__ dia, const float* __restrict__ off,
              const float* __restrict__ u_sel, float* __restrict__ vals,
              float* __restrict__ keep, int* __restrict__ kcnt) {
  __shared__ float d[256], e2[256];
  __shared__ float rlo[4], rhi[4];
  __shared__ int rk[4];
  const int tid = threadIdx.x;
  const int lane = tid & 63, wid = tid >> 6;
  d[tid] = dia[tid];
  float ev = (tid < 255) ? off[tid] : 0.0f;
  e2[tid] = ev * ev;
  __syncthreads();
  float ei = fabsf(ev);
  float eim = (tid > 0) ? fabsf(off[tid - 1]) : 0.0f;
  float mn = d[tid] - ei - eim, mx = d[tid] + ei + eim;
  for (int m = 32; m; m >>= 1) { mn = fminf(mn, __shfl_xor(mn, m)); mx = fmaxf(mx, __shfl_xor(mx, m)); }
  if (lane == 0) { rlo[wid] = mn; rhi[wid] = mx; }
  __syncthreads();
  float lo = fminf(fminf(rlo[0], rlo[1]), fminf(rlo[2], rlo[3])) - 1e-5f;
  float hi = fmaxf(fmaxf(rhi[0], rhi[1]), fmaxf(rhi[2], rhi[3])) + 1e-5f;
  for (int it = 0; it < 34; ++it) {
    float mid = 0.5f * (lo + hi);
    int cnt = 0;
    float q = d[0] - mid;
    if (fabsf(q) < 1e-25f) q = -1e-25f;
    cnt += (q < 0.0f);
    for (int i = 1; i < 256; ++i) {
      q = d[i] - mid - e2[i - 1] / q;
      if (fabsf(q) < 1e-25f) q = -1e-25f;
      cnt += (q < 0.0f);
    }
    if (cnt <= tid) lo = mid; else hi = mid;
  }
  float lam = 0.5f * (lo + hi);
  vals[tid] = lam;
  float kp = (u_sel[tid] < lam / (lam + 1.0f)) ? 1.0f : 0.0f;
  keep[tid] = kp;
  int ki = (int)kp;
  for (int m = 32; m; m >>= 1) ki += __shfl_xor(ki, m);
  if (lane == 0) rk[wid] = ki;
  __syncthreads();
  if (tid == 0) *kcnt = rk[0] + rk[1] + rk[2] + rk[3];
}

// ---------------------------------------------------------------- tridiagonal inverse iteration
__device__ __forceinline__ float dguard(float x) {
  return (x >= 0.0f) ? fmaxf(x, 1e-30f) : fminf(x, -1e-30f);
}
__device__ __forceinline__ float rndf(uint32_t x) {
  x ^= x >> 16; x *= 0x7feb352dU; x ^= x >> 15; x *= 0x846ca68bU; x ^= x >> 16;
  return ((float)(x & 0xFFFFFFu & 0xFFFFFF) * (1.0f / 16777216.0f)) * 2.0f - 1.0f;
}

__global__ __launch_bounds__(256)
void k_invit(const float* __restrict__ dia, const float* __restrict__ off,
             const float* __restrict__ vals,
             float* __restrict__ DD, float* __restrict__ DL, float* __restrict__ DU,
             float* __restrict__ DU2, float* __restrict__ PV, float* __restrict__ ZZ) {
  __shared__ float sd[256], se[256], sv[256];
  const int t = threadIdx.x;
  sd[t] = dia[t];
  se[t] = (t < 255) ? off[t] : 0.0f;
  sv[t] = vals[t];
  __syncthreads();
  const float lam = sv[t];
  for (int i = 0; i < 256; ++i) DD[i * 256 + t] = sd[i] - lam;
  for (int i = 0; i < 255; ++i) { DL[i * 256 + t] = se[i]; DU[i * 256 + t] = se[i]; DU2[i * 256 + t] = 0.0f; }
  // pivoted LU (LAPACK sgttrf)
  for (int i = 0; i < 255; ++i) {
    float di = DD[i * 256 + t], li = DL[i * 256 + t];
    if (fabsf(di) >= fabsf(li)) {
      float fact = (di != 0.0f) ? li / di : 0.0f;
      DL[i * 256 + t] = fact;
      DD[(i + 1) * 256 + t] -= fact * DU[i * 256 + t];
      PV[i * 256 + t] = 0.0f;
    } else {
      float fact = di / li;
      DD[i * 256 + t] = li;
      DL[i * 256 + t] = fact;
      float tmp = DU[i * 256 + t];
      float d1 = DD[(i + 1) * 256 + t];
      DU[i * 256 + t] = d1;
      DD[(i + 1) * 256 + t] = tmp - fact * d1;
      if (i < 254) {
        float dun = DU[(i + 1) * 256 + t];
        DU2[i * 256 + t] = dun;
        DU[(i + 1) * 256 + t] = -fact * dun;
      }
      PV[i * 256 + t] = 1.0f;
    }
  }
  for (int i = 0; i < 256; ++i) ZZ[i * 256 + t] = rndf((uint32_t)(i * 9781 + t * 65537 + 17));
  for (int pass = 0; pass < 2; ++pass) {
    for (int i = 0; i < 255; ++i) {
      float dl = DL[i * 256 + t];
      float b0 = ZZ[i * 256 + t], b1 = ZZ[(i + 1) * 256 + t];
      if (PV[i * 256 + t] == 0.0f) {
        ZZ[(i + 1) * 256 + t] = b1 - dl * b0;
      } else {
        ZZ[i * 256 + t] = b1;
        ZZ[(i + 1) * 256 + t] = b0 - dl * b1;
      }
    }
    float z2 = ZZ[255 * 256 + t] / dguard(DD[255 * 256 + t]);
    ZZ[255 * 256 + t] = z2;
    float z1 = (ZZ[254 * 256 + t] - DU[254 * 256 + t] * z2) / dguard(DD[254 * 256 + t]);
    ZZ[254 * 256 + t] = z1;
    for (int i = 253; i >= 0; --i) {
      float zi = (ZZ[i * 256 + t] - DU[i * 256 + t] * z1 - DU2[i * 256 + t] * z2) / dguard(DD[i * 256 + t]);
      ZZ[i * 256 + t] = zi;
      z2 = z1; z1 = zi;
    }
    double nn = 0.0;
    for (int i = 0; i < 256; ++i) { float z = ZZ[i * 256 + t]; nn += (double)z * (double)z; }
    float inv = (float)(1.0 / sqrt(fmax(nn, 1e-60)));
    for (int i = 0; i < 256; ++i) ZZ[i * 256 + t] *= inv;
  }
  __syncthreads();
  // cluster Gram-Schmidt (sequential within clusters)
  float ctol = 1e-3f * fmaxf(fabsf(sv[0]), fabsf(sv[255]));
  int cstart = t;
  while (cstart > 0 && (sv[cstart] - sv[cstart - 1]) <= ctol) --cstart;
  int crank = t - cstart;
  for (int c = 1; c < 16; ++c) {
    if (crank == c) {
      for (int q = cstart; q < t; ++q) {
        float dot = 0.0f;
        for (int i = 0; i < 256; ++i) dot += ZZ[i * 256 + q] * ZZ[i * 256 + t];
        for (int i = 0; i < 256; ++i) ZZ[i * 256 + t] -= dot * ZZ[i * 256 + q];
      }
      double nn = 0.0;
      for (int i = 0; i < 256; ++i) { float z = ZZ[i * 256 + t]; nn += (double)z * (double)z; }
      float inv = (float)(1.0 / sqrt(fmax(nn, 1e-60)));
      for (int i = 0; i < 256; ++i) ZZ[i * 256 + t] *= inv;
    }
    __syncthreads();
  }
}

// ---------------------------------------------------------------- back-transform: V = H * Z
__global__ __launch_bounds__(256)
void k_backxf(const float* __restrict__ ZZ, const float* __restrict__ refl,
              const float* __restrict__ tau, float* __restrict__ V) {
  __shared__ float zl[256][5];
  __shared__ float vbuf[256];
  const int tid = threadIdx.x;
  const int wid = tid >> 6, lane = tid & 63;
  const int l0 = blockIdx.x * 4;
  for (int i = tid; i < 256; i += 256)
#pragma unroll
    for (int c = 0; c < 4; ++c) zl[i][c] = ZZ[i * 256 + l0 + c];
  __syncthreads();
  for (int i = 253; i >= 0; --i) {
    for (int j = i + 1 + tid; j < 256; j += 256) vbuf[j] = refl[i * 256 + j];
    __syncthreads();
    float tv = tau[i];
    if (tv != 0.0f) {
      float s = 0.0f;
      for (int j = i + 1 + lane; j < 256; j += 64) s += vbuf[j] * zl[j][wid];
      for (int m = 32; m; m >>= 1) s += __shfl_xor(s, m);
      s *= tv;
      for (int j = i + 1 + lane; j < 256; j += 64) zl[j][wid] -= s * vbuf[j];
    }
    __syncthreads();
  }
  for (int i = tid; i < 256; i += 256)
#pragma unroll
    for (int c = 0; c < 4; ++c) V[i * 256 + (l0 + c)] = zl[i][c];
}

// ---------------------------------------------------------------- P = V_kept V_kept^T
__global__ __launch_bounds__(256)
void k_pbuild(const float* __restrict__ V, const float* __restrict__ keep, float* __restrict__ P) {
  __shared__ float sa[64][65], sb[64][65];
  const int tid = threadIdx.x;
  const int i0 = blockIdx.y * 64, j0 = blockIdx.x * 64;
  const int ti = tid >> 4, tj = tid & 15;
  float acc[4][4];
#pragma unroll
  for (int a = 0; a < 4; ++a)
#pragma unroll
    for (int b = 0; b < 4; ++b) acc[a][b] = 0.0f;
  for (int c0 = 0; c0 < 256; c0 += 64) {
    for (int q = tid; q < 64 * 64; q += 256) {
      int r = q >> 6, c = q & 63;
      sa[r][c] = V[(i0 + r) * 256 + c0 + c] * keep[c0 + c];
      sb[r][c] = V[(j0 + r) * 256 + c0 + c];
    }
    __syncthreads();
    for (int c = 0; c < 64; ++c)
#pragma unroll
      for (int a = 0; a < 4; ++a)
#pragma unroll
        for (int b = 0; b < 4; ++b) acc[a][b] += sa[ti * 4 + a][c] * sb[tj * 4 + b][c];
    __syncthreads();
  }
#pragma unroll
  for (int a = 0; a < 4; ++a)
#pragma unroll
    for (int b = 0; b < 4; ++b) P[(i0 + ti * 4 + a) * 256 + j0 + tj * 4 + b] = acc[a][b];
}

// ---------------------------------------------------------------- DPP sampling (incremental Schur)
// p_t = diag(P) - rowsum(M^2);  sample item by inverse-CDF on p/S;  append column
// m = (P[:,s] - M M[s,:]^T)/sqrt(p_s).  M: first 148 cols in LDS, rest in global.
__global__ void k_dpp(const float* __restrict__ P, const int* __restrict__ kcnt,
                      const float* __restrict__ u_item,
                      float* __restrict__ MG, float* __restrict__ subset) {
  extern __shared__ float lds[];
  float* M = lds;                   // [256][148]
  float* p = lds + 256 * 148;       // 256
  float* subs = p + 256;            // 256
  const int lane = threadIdx.x;     // 64 threads = 1 wave
  const int k = *kcnt;
  for (int r = lane; r < 256; r += 64) { subs[r] = 0.0f; p[r] = P[r * 256 + r]; }
  __syncthreads();
  const bool allsel = (k >= 256);
  const int kk = allsel ? 0 : k;
  for (int t = 0; t < kk; ++t) {
    float4 pv = *(const float4*)&p[lane * 4];
    float lsum = pv.x + pv.y + pv.z + pv.w;
    float S = lsum;
    for (int m = 32; m; m >>= 1) S += __shfl_xor(S, m);
    if (S < 1e-12f) S = 1e-12f;
    float q0 = pv.x / S, q1 = pv.y / S, q2 = pv.z / S, q3 = pv.w / S;
    float c0 = q0, c1 = c0 + q1, c2 = c1 + q2, c3 = c2 + q3;
    float sc = c3;
    for (int o = 1; o < 64; o <<= 1) { float v = __shfl_up(sc, o); if (lane >= o) sc += v; }
    float excl = sc - c3;
    float u = u_item[t];
    int mf = 4;
    if (u < excl + c3) mf = 3;
    if (u < excl + c2) mf = 2;
    if (u < excl + c1) mf = 1;
    if (u < excl + c0) mf = 0;
    unsigned long long ball = __ballot(mf < 4);
    int item = 0;
    if (ball != 0ULL) {
      int fl = __ffsll(ball) - 1;
      int fj = __shfl(mf, fl);
      item = fl * 4 + fj;
    }
    if (lane == 0) subs[item] = 1.0f;
    // dot[g] = sum_c M[r][c]*M[item][c], rows r = lane + 64g
    float dot[4] = {0.f, 0.f, 0.f, 0.f};
    int tl = (t < 148) ? t : 148;
    int c4 = tl & ~3;
    for (int c = 0; c < c4; c += 4) {
      float4 mb = *(const float4*)&M[item * 148 + c];
#pragma unroll
      for (int g = 0; g < 4; ++g) {
        float4 mr = *(const float4*)&M[(lane + 64 * g) * 148 + c];
        dot[g] += mr.x * mb.x + mr.y * mb.y + mr.z * mb.z + mr.w * mb.w;
      }
    }
    for (int c = c4; c < tl; ++c) {
      float mb = M[item * 148 + c];
#pragma unroll
      for (int g = 0; g < 4; ++g) dot[g] += M[(lane + 64 * g) * 148 + c] * mb;
    }
    for (int c = 148; c < t; ++c) {
      float mb = MG[(c - 148) * 256 + item];
#pragma unroll
      for (int g = 0; g < 4; ++g) dot[g] += MG[(c - 148) * 256 + lane + 64 * g] * mb;
    }
    float pit = p[item];
    float rs = 1.0f / sqrtf(fmaxf(pit, 1e-30f));
#pragma unroll
    for (int g = 0; g < 4; ++g) {
      int r = lane + 64 * g;
      float mn = (P[(size_t)item * 256 + r] - dot[g]) * rs;
      float pn = p[r] - mn * mn;
      p[r] = fmaxf(pn, 0.0f);
      if (t < 148) M[r * 148 + t] = mn;
      else MG[(t - 148) * 256 + r] = mn;
    }
    __syncthreads();
  }
  __syncthreads();
  for (int r = lane; r < 256; r += 64) subset[r] = allsel ? 1.0f : subs[r];
}

// ---------------------------------------------------------------- tail
__global__ void k_pick(const float* __restrict__ subset, const float* __restrict__ words,
                       float* __restrict__ pick) {
  __shared__ float s[256];
  const int tid = threadIdx.x;
  s[tid] = subset[tid];
  __syncthreads();
  const int c = blockIdx.x * 256 + tid;
  float acc = 0.0f;
  for (int r = 0; r < 256; ++r) acc += s[r] * words[r * 2048 + c];
  pick[c] = acc;
}

__global__ void k_p1(const float* __restrict__ pick, const float* __restrict__ W,
                     const float* __restrict__ b, float* __restrict__ p1) {
  __shared__ float s[2048];
  const int tid = threadIdx.x;
  for (int i = tid; i < 2048; i += 256) s[i] = pick[i];
  __syncthreads();
  const int n = blockIdx.x * 256 + tid;
  float acc = b[n];
  for (int r = 0; r < 2048; ++r) acc += s[r] * W[(size_t)r * 4096 + n];
  p1[n] = fmaxf(acc, 0.0f);
}

__global__ void k_final(const float* __restrict__ p1, const float* __restrict__ w2,
                        const float* __restrict__ b2, float* __restrict__ out) {
  __shared__ float red[4];
  const int tid = threadIdx.x;
  float acc = 0.0f;
  for (int i = tid; i < 4096; i += 256) acc += p1[i] * w2[i];
  for (int m = 32; m; m >>= 1) acc += __shfl_xor(acc, m);
  if ((tid & 63) == 0) red[tid >> 6] = acc;
  __syncthreads();
  if (tid == 0) out[0] = red[0] + red[1] + red[2] + red[3] + b2[0];
}

// ---------------------------------------------------------------- launch
extern "C" void kernel_launch(void* const* d_in, const int* in_sizes, int n_in,
                              void* d_out, int out_size, void* d_ws, size_t ws_size,
                              hipStream_t stream) {
  const float* words = (const float*)d_in[0];
  const float* ctx   = (const float*)d_in[1];
  const float* ew1   = (const float*)d_in[2];
  const float* eb1   = (const float*)d_in[3];
  const float* ew2   = (const float*)d_in[4];
  const float* eb2   = (const float*)d_in[5];
  const float* pw1   = (const float*)d_in[6];
  const float* pb1   = (const float*)d_in[7];
  const float* pw2   = (const float*)d_in[8];
  const float* pb2   = (const float*)d_in[9];
  const float* usel  = (const float*)d_in[10];
  const float* uitem = (const float*)d_in[11];
  (void)in_sizes; (void)n_in; (void)out_size; (void)ws_size;
  char* w = (char*)d_ws;

  f16* xh = (f16*)(w + 0);
  f16* xl = (f16*)(w + (size_t)(2 << 20));
  f16* hh = (f16*)(w + (size_t)(4 << 20));
  f16* hl = (f16*)(w + (size_t)(8 << 20));
  f16* Eh = (f16*)(w + (size_t)(12 << 20));
  f16* El = (f16*)(w + (size_t)(14 << 20));
  size_t o = (size_t)(16 << 20);
  float* Km   = (float*)(w + o); o += 262144;
  float* dda  = (float*)(w + o); o += 1024;
  float* ee   = (float*)(w + o); o += 1024;
  float* tt   = (float*)(w + o); o += 1024;
  float* vals = (float*)(w + o); o += 1024;
  float* keep = (float*)(w + o); o += 1024;
  int*   kcnt = (int*)  (w + o); o += 1024;
  float* refl = (float*)(w + o); o += 262144;
  float* ZZ   = (float*)(w + o); o += 262144;
  float* V    = (float*)(w + o); o += 262144;
  float* P    = (float*)(w + o); o += 262144;
  float* DD   = (float*)(w + o); o += 262144;
  float* DL   = (float*)(w + o); o += 262144;
  float* DU   = (float*)(w + o); o += 262144;
  float* DU2  = (float*)(w + o); o += 262144;
  float* PVp  = (float*)(w + o); o += 262144;
  float* MG   = (float*)(w + o); o += 131072;
  float* subset = (float*)(w + o); o += 1024;
  float* pick = (float*)(w + o); o += 8192;
  float* p1   = (float*)(w + o); o += 16384;

  hipFuncSetAttribute((const void*)k_tridiag, hipFuncAttributeMaxDynamicSharedMemorySize, 140000);
  hipFuncSetAttribute((const void*)k_dpp,     hipFuncAttributeMaxDynamicSharedMemorySize, 156000);

  k_split_x<<<4096, 256, 0, stream>>>(words, ctx, xh, xl);
  k_gemm_split<true ><<<dim3(128, 2), 256, 0, stream>>>(xh, xl, ew1, eb1, hh, hl, 256, 8192, 4096);
  k_gemm_split<false><<<dim3( 64, 2), 256, 0, stream>>>(hh, hl, ew2, eb2, Eh, El, 256, 4096, 8192);
  k_kgemm<<<dim3(4, 4), 256, 0, stream>>>(Eh, El, Km);
  k_tridiag<<<1, 1024, 134736, stream>>>(Km, dda, ee, refl, tt);
  k_bisect<<<1, 256, 0, stream>>>(dda, ee, usel, vals, keep, kcnt);
  k_invit<<<1, 256, 0, stream>>>(dda, ee, vals, DD, DL, DU, DU2, PVp, ZZ);
  k_backxf<<<64, 256, 0, stream>>>(ZZ, refl, tt, V);
  k_pbuild<<<dim3(4, 4), 256, 0, stream>>>(V, keep, P);
  k_dpp<<<1, 64, 153600, stream>>>(P, kcnt, uitem, MG, subset);
  k_pick<<<8, 256, 0, stream>>>(subset, words, pick);
  k_p1<<<16, 256, 0, stream>>>(pick, pw1, pb1, p1);
  k_final<<<1, 256, 0, stream>>>(p1, pw2, pb2, (float*)d_out);
}

// Round 2
// 9148.128 us; speedup vs baseline: 1.0417x; 1.0417x over previous
//
#include <hip/hip_runtime.h>
#include <hip/hip_fp16.h>
#include <stdint.h>

typedef _Float16 f16;
typedef __attribute__((ext_vector_type(8))) _Float16 f16x8;
typedef __attribute__((ext_vector_type(4))) float f32x4;

// fp32 -> (hi, lo*2^11) fp16 split (Markidis).  a ~= hi + lo/2048.
__device__ __forceinline__ void splitf(float v, f16& h, f16& l) {
  f16 hh = (f16)v;
  h = hh;
  l = (f16)((v - (float)hh) * 2048.0f);
}

// ---------------------------------------------------------------- x concat+split
__global__ void k_split_x(const float* __restrict__ words, const float* __restrict__ ctx,
                          f16* __restrict__ xh, f16* __restrict__ xl) {
  int idx = blockIdx.x * 256 + threadIdx.x;   // 256*4096 elements
  int c = idx & 4095;
  int r = idx >> 12;
  float v = (c < 2048) ? words[r * 2048 + c] : ctx[r * 2048 + (c - 2048)];
  f16 h, l; splitf(v, h, l);
  xh[idx] = h; xl[idx] = l;
}

// ---------------------------------------------------------------- split-fp16 GEMM
// C(M x Nn) = A(M x K) * B(K x Nn) + bias, A pre-split f16 hi/lo, B fp32 converted
// on the fly.  Tiles: BM=128, BN=64, BK=32.  4 waves (2x2), wave tile 64x32.
template<bool ELU>
__global__ __launch_bounds__(256)
void k_gemm_split(const f16* __restrict__ Ah, const f16* __restrict__ Al,
                  const float* __restrict__ B, const float* __restrict__ bias,
                  f16* __restrict__ Ch, f16* __restrict__ Cl,
                  int M, int Nn, int K) {
  __shared__ f16 sA[2][2][128 * 32];
  __shared__ f16 sB[2][2][4 * 65 * 8];
  const int tid = threadIdx.x;
  const int m0 = blockIdx.y * 128;
  const int n0 = blockIdx.x * 64;
  const int wid = tid >> 6, lane = tid & 63;
  const int wm = (wid >> 1) * 64, wn = (wid & 1) * 32;
  const int lx = lane & 15, lg = lane >> 4;

  f32x4 zero = {0.f, 0.f, 0.f, 0.f};
  f32x4 acc_h[4][2], acc_x[4][2];
#pragma unroll
  for (int i = 0; i < 4; ++i)
#pragma unroll
    for (int j = 0; j < 2; ++j) { acc_h[i][j] = zero; acc_x[i][j] = zero; }

  const int NT = K >> 5;

  auto stage = [&](int ktile, int bufi) {
    int row = tid >> 1, half = tid & 1;
    size_t gof = (size_t)(m0 + row) * K + (size_t)ktile * 32 + half * 16;
    int lof = row * 32 + half * 16;
    *(f16x8*)&sA[bufi][0][lof]     = *(const f16x8*)(Ah + gof);
    *(f16x8*)&sA[bufi][0][lof + 8] = *(const f16x8*)(Ah + gof + 8);
    *(f16x8*)&sA[bufi][1][lof]     = *(const f16x8*)(Al + gof);
    *(f16x8*)&sA[bufi][1][lof + 8] = *(const f16x8*)(Al + gof + 8);
    int kk = tid >> 3, nb = (tid & 7) * 8;
    const float* gp = B + (size_t)((size_t)ktile * 32 + kk) * Nn + n0 + nb;
    float4 v0 = *(const float4*)gp;
    float4 v1 = *(const float4*)(gp + 4);
    float vv[8] = {v0.x, v0.y, v0.z, v0.w, v1.x, v1.y, v1.z, v1.w};
    int gi = kk >> 3, jj = kk & 7;
#pragma unroll
    for (int q = 0; q < 8; ++q) {
      f16 hh, ll; splitf(vv[q], hh, ll);
      sB[bufi][0][gi * 520 + (nb + q) * 8 + jj] = hh;
      sB[bufi][1][gi * 520 + (nb + q) * 8 + jj] = ll;
    }
  };

  stage(0, 0);
  int buf = 0;
  for (int kt = 0; kt < NT; ++kt) {
    __syncthreads();
    if (kt + 1 < NT) stage(kt + 1, buf ^ 1);
    f16x8 a_h[4], a_l[4], b_h[2], b_l[2];
#pragma unroll
    for (int mi = 0; mi < 4; ++mi) {
      int row = wm + mi * 16 + lx;
      a_h[mi] = *(const f16x8*)&sA[buf][0][row * 32 + lg * 8];
      a_l[mi] = *(const f16x8*)&sA[buf][1][row * 32 + lg * 8];
    }
#pragma unroll
    for (int ni = 0; ni < 2; ++ni) {
      int col = wn + ni * 16 + lx;
      b_h[ni] = *(const f16x8*)&sB[buf][0][lg * 520 + col * 8];
      b_l[ni] = *(const f16x8*)&sB[buf][1][lg * 520 + col * 8];
    }
#pragma unroll
    for (int mi = 0; mi < 4; ++mi)
#pragma unroll
      for (int ni = 0; ni < 2; ++ni) {
        acc_h[mi][ni] = __builtin_amdgcn_mfma_f32_16x16x32_f16(a_h[mi], b_h[ni], acc_h[mi][ni], 0, 0, 0);
        acc_x[mi][ni] = __builtin_amdgcn_mfma_f32_16x16x32_f16(a_h[mi], b_l[ni], acc_x[mi][ni], 0, 0, 0);
        acc_x[mi][ni] = __builtin_amdgcn_mfma_f32_16x16x32_f16(a_l[mi], b_h[ni], acc_x[mi][ni], 0, 0, 0);
      }
    buf ^= 1;
  }
#pragma unroll
  for (int mi = 0; mi < 4; ++mi)
#pragma unroll
    for (int ni = 0; ni < 2; ++ni) {
      int col = n0 + wn + ni * 16 + lx;
      float bs = bias[col];
#pragma unroll
      for (int r = 0; r < 4; ++r) {
        int row = m0 + wm + mi * 16 + lg * 4 + r;
        float c = acc_h[mi][ni][r] + acc_x[mi][ni][r] * (1.0f / 2048.0f) + bs;
        if (ELU) c = (c > 0.0f) ? c : expm1f(c);
        f16 hh, ll; splitf(c, hh, ll);
        size_t o = (size_t)row * Nn + col;
        Ch[o] = hh; Cl[o] = ll;
      }
    }
}

// ---------------------------------------------------------------- K = E E^T
__global__ __launch_bounds__(256)
void k_kgemm(const f16* __restrict__ Eh, const f16* __restrict__ El, float* __restrict__ Kout) {
  const int tid = threadIdx.x;
  const int wid = tid >> 6, lane = tid & 63;
  const int m0 = blockIdx.y * 64 + (wid >> 1) * 32;
  const int n0 = blockIdx.x * 64 + (wid & 1) * 32;
  const int lx = lane & 15, lg = lane >> 4;
  f32x4 zero = {0.f, 0.f, 0.f, 0.f};
  f32x4 acc_h[2][2], acc_x[2][2];
#pragma unroll
  for (int i = 0; i < 2; ++i)
#pragma unroll
    for (int j = 0; j < 2; ++j) { acc_h[i][j] = zero; acc_x[i][j] = zero; }
  for (int kt = 0; kt < 128; ++kt) {
    f16x8 ah[2], al[2], bh[2], bl[2];
#pragma unroll
    for (int mi = 0; mi < 2; ++mi) {
      size_t o = (size_t)(m0 + mi * 16 + lx) * 4096 + kt * 32 + lg * 8;
      ah[mi] = *(const f16x8*)(Eh + o);
      al[mi] = *(const f16x8*)(El + o);
    }
#pragma unroll
    for (int ni = 0; ni < 2; ++ni) {
      size_t o = (size_t)(n0 + ni * 16 + lx) * 4096 + kt * 32 + lg * 8;
      bh[ni] = *(const f16x8*)(Eh + o);
      bl[ni] = *(const f16x8*)(El + o);
    }
#pragma unroll
    for (int mi = 0; mi < 2; ++mi)
#pragma unroll
      for (int ni = 0; ni < 2; ++ni) {
        acc_h[mi][ni] = __builtin_amdgcn_mfma_f32_16x16x32_f16(ah[mi], bh[ni], acc_h[mi][ni], 0, 0, 0);
        acc_x[mi][ni] = __builtin_amdgcn_mfma_f32_16x16x32_f16(ah[mi], bl[ni], acc_x[mi][ni], 0, 0, 0);
        acc_x[mi][ni] = __builtin_amdgcn_mfma_f32_16x16x32_f16(al[mi], bh[ni], acc_x[mi][ni], 0, 0, 0);
      }
  }
#pragma unroll
  for (int mi = 0; mi < 2; ++mi)
#pragma unroll
    for (int ni = 0; ni < 2; ++ni)
#pragma unroll
      for (int r = 0; r < 4; ++r)
        Kout[(m0 + mi * 16 + lg * 4 + r) * 256 + n0 + ni * 16 + lx] =
            acc_h[mi][ni][r] + acc_x[mi][ni][r] * (1.0f / 2048.0f);
}

// ---------------------------------------------------------------- Householder tridiagonalization
__global__ __launch_bounds__(1024)
void k_tridiag(const float* __restrict__ Kin, float* __restrict__ dia,
               float* __restrict__ off, float* __restrict__ refl, float* __restrict__ tau) {
  extern __shared__ float lds[];
  float* A   = lds;            // 32896 floats packed lower triangle
  float* vv  = lds + 32896;    // 256
  float* ww  = vv + 256;       // 256
  float* uu  = ww + 256;       // 256
  float* red = uu + 256;       // 16
  float* scal = red + 16;      // 4
  const int tid = threadIdx.x;
  const int lane = tid & 63, wid = tid >> 6;

  for (int j = tid >> 2; j < 256; j += 256) {
    int base = (j * (j + 1)) >> 1;
    for (int kq = (tid & 3); kq <= j; kq += 4) A[base + kq] = Kin[j * 256 + kq];
  }
  __syncthreads();

  for (int i = 0; i < 254; ++i) {
    const int lo = i + 1;
    for (int j = lo + tid; j < 256; j += 1024) vv[j] = A[((j * (j + 1)) >> 1) + i];
    __syncthreads();
    float ps = 0.0f;
    for (int j = lo + 1 + tid; j < 256; j += 1024) { float x = vv[j]; ps += x * x; }
    for (int m = 32; m; m >>= 1) ps += __shfl_xor(ps, m);
    if (lane == 0) red[wid] = ps;
    __syncthreads();
    if (tid == 0) {
      float sig = 0.0f;
      for (int wq = 0; wq < 16; ++wq) sig += red[wq];
      float alpha = vv[lo];
      float tv, inv, beta;
      if (sig <= 1e-35f) { beta = alpha; tv = 0.0f; inv = 0.0f; }
      else {
        float mu = sqrtf(alpha * alpha + sig);
        beta = (alpha > 0.0f) ? -mu : mu;
        tv = (beta - alpha) / beta;
        inv = 1.0f / (alpha - beta);
      }
      scal[0] = tv; scal[1] = inv;
      dia[i] = A[((i * (i + 1)) >> 1) + i];
      off[i] = beta;
      tau[i] = tv;
    }
    __syncthreads();
    const float tv = scal[0], inv = scal[1];
    for (int j = lo + tid; j < 256; j += 1024) {
      float v = (j == lo) ? ((tv != 0.0f) ? 1.0f : 0.0f) : vv[j] * inv;
      vv[j] = v;
      refl[i * 256 + j] = v;
    }
    __syncthreads();
    for (int j = lo + wid; j < 256; j += 16) {
      const float* Ar = A + ((j * (j + 1)) >> 1);
      float s = 0.0f;
      for (int kq = lo + lane; kq <= j; kq += 64) s += Ar[kq] * vv[kq];
      for (int m = 32; m; m >>= 1) s += __shfl_xor(s, m);
      if (lane == 0) ww[j] = s;
    }
    __syncthreads();
    for (int kq = lo + wid; kq < 256; kq += 16) {
      float s = 0.0f;
      for (int j = kq + 1 + lane; j < 256; j += 64) s += A[((j * (j + 1)) >> 1) + kq] * vv[j];
      for (int m = 32; m; m >>= 1) s += __shfl_xor(s, m);
      if (lane == 0) ww[kq] += s;
    }
    __syncthreads();
    float pp = 0.0f;
    for (int j = lo + tid; j < 256; j += 1024) pp += vv[j] * ww[j];
    for (int m = 32; m; m >>= 1) pp += __shfl_xor(pp, m);
    if (lane == 0) red[wid] = pp;
    __syncthreads();
    if (tid == 0) {
      float pw = 0.0f;
      for (int wq = 0; wq < 16; ++wq) pw += red[wq];
      scal[2] = pw;
    }
    __syncthreads();
    const float hc = 0.5f * tv * tv * scal[2];
    for (int j = lo + tid; j < 256; j += 1024) uu[j] = tv * ww[j] - hc * vv[j];
    __syncthreads();
    for (int j = lo + wid; j < 256; j += 16) {
      float vj = vv[j], uj = uu[j];
      float* Ar = A + ((j * (j + 1)) >> 1);
      for (int kq = lo + lane; kq <= j; kq += 64) Ar[kq] -= vj * uu[kq] + uj * vv[kq];
    }
    __syncthreads();
  }
  if (tid == 0) {
    dia[254] = A[((254 * 255) >> 1) + 254];
    dia[255] = A[((255 * 256) >> 1) + 255];
    off[254] = A[((255 * 256) >> 1) + 254];
    off[255] = 0.0f;
    tau[254] = 0.0f; tau[255] = 0.0f;
  }
}

// ---------------------------------------------------------------- bisection eigenvalues + keep
__global__ __launch_bounds__(256)
void k_bisect(const float* __restrict__ dia, const float* __restrict__ off,
              const float* __restrict__ u_sel, float* __restrict__ vals,
              float* __restrict__ keep, int* __restrict__ kcnt) {
  __shared__ float d[256], e2[256];
  __shared__ float rlo[4], rhi[4];
  __shared__ int rk[4];
  const int tid = threadIdx.x;
  const int lane = tid & 63, wid = tid >> 6;
  d[tid] = dia[tid];
  float ev = (tid < 255) ? off[tid] : 0.0f;
  e2[tid] = ev * ev;
  __syncthreads();
  float ei = fabsf(ev);
  float eim = (tid > 0) ? fabsf(off[tid - 1]) : 0.0f;
  float mn = d[tid] - ei - eim, mx = d[tid] + ei + eim;
  for (int m = 32; m; m >>= 1) { mn = fminf(mn, __shfl_xor(mn, m)); mx = fmaxf(mx, __shfl_xor(mx, m)); }
  if (lane == 0) { rlo[wid] = mn; rhi[wid] = mx; }
  __syncthreads();
  float lo = fminf(fminf(rlo[0], rlo[1]), fminf(rlo[2], rlo[3])) - 1e-5f;
  float hi = fmaxf(fmaxf(rhi[0], rhi[1]), fmaxf(rhi[2], rhi[3])) + 1e-5f;
  for (int it = 0; it < 34; ++it) {
    float mid = 0.5f * (lo + hi);
    int cnt = 0;
    float q = d[0] - mid;
    if (fabsf(q) < 1e-25f) q = -1e-25f;
    cnt += (q < 0.0f);
    for (int i = 1; i < 256; ++i) {
      q = d[i] - mid - e2[i - 1] / q;
      if (fabsf(q) < 1e-25f) q = -1e-25f;
      cnt += (q < 0.0f);
    }
    if (cnt <= tid) lo = mid; else hi = mid;
  }
  float lam = 0.5f * (lo + hi);
  vals[tid] = lam;
  float kp = (u_sel[tid] < lam / (lam + 1.0f)) ? 1.0f : 0.0f;
  keep[tid] = kp;
  int ki = (int)kp;
  for (int m = 32; m; m >>= 1) ki += __shfl_xor(ki, m);
  if (lane == 0) rk[wid] = ki;
  __syncthreads();
  if (tid == 0) *kcnt = rk[0] + rk[1] + rk[2] + rk[3];
}

// ---------------------------------------------------------------- tridiagonal inverse iteration
// Rewritten: streaming register-resident LU (store-only factor stream F = float4
// (DD,DU,DU2,DL) + pivot bitmask), then pipelined fwd/back substitution reading
// the L2-resident factor stream.  Removes all dependent global round-trips.
__device__ __forceinline__ float dguard(float x) {
  return (x >= 0.0f) ? fmaxf(x, 1e-30f) : fminf(x, -1e-30f);
}
__device__ __forceinline__ float rndf(uint32_t x) {
  x ^= x >> 16; x *= 0x7feb352dU; x ^= x >> 15; x *= 0x846ca68bU; x ^= x >> 16;
  return ((float)(x & 0xFFFFFFu & 0xFFFFFF) * (1.0f / 16777216.0f)) * 2.0f - 1.0f;
}

__global__ __launch_bounds__(256)
void k_invit(const float* __restrict__ dia, const float* __restrict__ off,
             const float* __restrict__ vals,
             float4* __restrict__ F, uint32_t* __restrict__ pvm, float* __restrict__ ZZ) {
  __shared__ float sd[256], se[256], sv[256];
  const int t = threadIdx.x;
  sd[t] = dia[t];
  se[t] = (t < 255) ? off[t] : 0.0f;
  sv[t] = vals[t];
  __syncthreads();
  const float lam = sv[t];

  // Phase A: streaming pivoted LU of (T - lam I); carries d_cur, u_cur in regs.
  {
    float d_cur = sd[0] - lam;
    float u_cur = se[0];
    uint32_t bits = 0;
    for (int i = 0; i < 255; ++i) {
      const float li = se[i];
      const float d1 = sd[i + 1] - lam;
      const float uin = (i < 254) ? se[i + 1] : 0.0f;
      float dd_i, du_i, du2_i, dl_i;
      if (fabsf(d_cur) >= fabsf(li)) {
        float fact = (d_cur != 0.0f) ? li / d_cur : 0.0f;
        dd_i = d_cur; du_i = u_cur; du2_i = 0.0f; dl_i = fact;
        d_cur = d1 - fact * u_cur;
        u_cur = uin;
      } else {
        float fact = d_cur / li;
        dd_i = li; du_i = d1; du2_i = uin; dl_i = fact;
        d_cur = u_cur - fact * d1;
        u_cur = -fact * uin;
        bits |= (1u << (i & 31));
      }
      F[i * 256 + t] = make_float4(dd_i, du_i, du2_i, dl_i);
      if ((i & 31) == 31) { pvm[(i >> 5) * 256 + t] = bits; bits = 0; }
    }
    pvm[7 * 256 + t] = bits;                        // i = 224..254
    F[255 * 256 + t] = make_float4(d_cur, 0.0f, 0.0f, 0.0f);
  }

  for (int pass = 0; pass < 2; ++pass) {
    // forward substitution (streaming, 2-elem window in regs)
    float b = (pass == 0) ? rndf((uint32_t)(t * 65537 + 17)) : ZZ[t];
    uint32_t w = 0;
    for (int i = 0; i < 255; ++i) {
      if ((i & 31) == 0) w = pvm[(i >> 5) * 256 + t];
      float4 f = F[i * 256 + t];
      float b1 = (pass == 0) ? rndf((uint32_t)((i + 1) * 9781 + t * 65537 + 17))
                             : ZZ[(i + 1) * 256 + t];
      float outv, bn;
      if (w & (1u << (i & 31))) { outv = b1; bn = b - f.w * b1; }
      else                      { outv = b;  bn = b1 - f.w * b; }
      ZZ[i * 256 + t] = outv;
      b = bn;
    }
    ZZ[255 * 256 + t] = b;

    // back substitution + norm accumulation
    float4 f2 = F[255 * 256 + t];
    float z2 = ZZ[255 * 256 + t] / dguard(f2.x);
    ZZ[255 * 256 + t] = z2;
    float4 f1 = F[254 * 256 + t];
    float z1 = (ZZ[254 * 256 + t] - f1.y * z2) / dguard(f1.x);
    ZZ[254 * 256 + t] = z1;
    double nn = (double)z2 * (double)z2 + (double)z1 * (double)z1;
    for (int i = 253; i >= 0; --i) {
      float4 f = F[i * 256 + t];
      float zi = (ZZ[i * 256 + t] - f.y * z1 - f.z * z2) / dguard(f.x);
      ZZ[i * 256 + t] = zi;
      nn += (double)zi * (double)zi;
      z2 = z1; z1 = zi;
    }
    float inv = (float)(1.0 / sqrt(fmax(nn, 1e-60)));
    for (int i = 0; i < 256; ++i) ZZ[i * 256 + t] *= inv;
  }
  __syncthreads();
  // cluster Gram-Schmidt (sequential within clusters)
  float ctol = 1e-3f * fmaxf(fabsf(sv[0]), fabsf(sv[255]));
  int cstart = t;
  while (cstart > 0 && (sv[cstart] - sv[cstart - 1]) <= ctol) --cstart;
  int crank = t - cstart;
  for (int c = 1; c < 16; ++c) {
    if (crank == c) {
      for (int q = cstart; q < t; ++q) {
        float dot = 0.0f;
        for (int i = 0; i < 256; ++i) dot += ZZ[i * 256 + q] * ZZ[i * 256 + t];
        for (int i = 0; i < 256; ++i) ZZ[i * 256 + t] -= dot * ZZ[i * 256 + q];
      }
      double nn = 0.0;
      for (int i = 0; i < 256; ++i) { float z = ZZ[i * 256 + t]; nn += (double)z * (double)z; }
      float inv = (float)(1.0 / sqrt(fmax(nn, 1e-60)));
      for (int i = 0; i < 256; ++i) ZZ[i * 256 + t] *= inv;
    }
    __syncthreads();
  }
}

// ---------------------------------------------------------------- back-transform: V = H * Z
__global__ __launch_bounds__(256)
void k_backxf(const float* __restrict__ ZZ, const float* __restrict__ refl,
              const float* __restrict__ tau, float* __restrict__ V) {
  __shared__ float zl[256][5];
  __shared__ float vbuf[256];
  const int tid = threadIdx.x;
  const int wid = tid >> 6, lane = tid & 63;
  const int l0 = blockIdx.x * 4;
  for (int i = tid; i < 256; i += 256)
#pragma unroll
    for (int c = 0; c < 4; ++c) zl[i][c] = ZZ[i * 256 + l0 + c];
  __syncthreads();
  for (int i = 253; i >= 0; --i) {
    for (int j = i + 1 + tid; j < 256; j += 256) vbuf[j] = refl[i * 256 + j];
    __syncthreads();
    float tv = tau[i];
    if (tv != 0.0f) {
      float s = 0.0f;
      for (int j = i + 1 + lane; j < 256; j += 64) s += vbuf[j] * zl[j][wid];
      for (int m = 32; m; m >>= 1) s += __shfl_xor(s, m);
      s *= tv;
      for (int j = i + 1 + lane; j < 256; j += 64) zl[j][wid] -= s * vbuf[j];
    }
    __syncthreads();
  }
  for (int i = tid; i < 256; i += 256)
#pragma unroll
    for (int c = 0; c < 4; ++c) V[i * 256 + (l0 + c)] = zl[i][c];
}

// ---------------------------------------------------------------- P = V_kept V_kept^T
__global__ __launch_bounds__(256)
void k_pbuild(const float* __restrict__ V, const float* __restrict__ keep, float* __restrict__ P) {
  __shared__ float sa[64][65], sb[64][65];
  const int tid = threadIdx.x;
  const int i0 = blockIdx.y * 64, j0 = blockIdx.x * 64;
  const int ti = tid >> 4, tj = tid & 15;
  float acc[4][4];
#pragma unroll
  for (int a = 0; a < 4; ++a)
#pragma unroll
    for (int b = 0; b < 4; ++b) acc[a][b] = 0.0f;
  for (int c0 = 0; c0 < 256; c0 += 64) {
    for (int q = tid; q < 64 * 64; q += 256) {
      int r = q >> 6, c = q & 63;
      sa[r][c] = V[(i0 + r) * 256 + c0 + c] * keep[c0 + c];
      sb[r][c] = V[(j0 + r) * 256 + c0 + c];
    }
    __syncthreads();
    for (int c = 0; c < 64; ++c)
#pragma unroll
      for (int a = 0; a < 4; ++a)
#pragma unroll
        for (int b = 0; b < 4; ++b) acc[a][b] += sa[ti * 4 + a][c] * sb[tj * 4 + b][c];
    __syncthreads();
  }
#pragma unroll
  for (int a = 0; a < 4; ++a)
#pragma unroll
    for (int b = 0; b < 4; ++b) P[(i0 + ti * 4 + a) * 256 + j0 + tj * 4 + b] = acc[a][b];
}

// ---------------------------------------------------------------- DPP sampling (incremental Schur)
__global__ void k_dpp(const float* __restrict__ P, const int* __restrict__ kcnt,
                      const float* __restrict__ u_item,
                      float* __restrict__ MG, float* __restrict__ subset) {
  extern __shared__ float lds[];
  float* M = lds;                   // [256][148]
  float* p = lds + 256 * 148;       // 256
  float* subs = p + 256;            // 256
  const int lane = threadIdx.x;     // 64 threads = 1 wave
  const int k = *kcnt;
  for (int r = lane; r < 256; r += 64) { subs[r] = 0.0f; p[r] = P[r * 256 + r]; }
  __syncthreads();
  const bool allsel = (k >= 256);
  const int kk = allsel ? 0 : k;
  for (int t = 0; t < kk; ++t) {
    float4 pv = *(const float4*)&p[lane * 4];
    float lsum = pv.x + pv.y + pv.z + pv.w;
    float S = lsum;
    for (int m = 32; m; m >>= 1) S += __shfl_xor(S, m);
    if (S < 1e-12f) S = 1e-12f;
    float q0 = pv.x / S, q1 = pv.y / S, q2 = pv.z / S, q3 = pv.w / S;
    float c0 = q0, c1 = c0 + q1, c2 = c1 + q2, c3 = c2 + q3;
    float sc = c3;
    for (int o = 1; o < 64; o <<= 1) { float v = __shfl_up(sc, o); if (lane >= o) sc += v; }
    float excl = sc - c3;
    float u = u_item[t];
    int mf = 4;
    if (u < excl + c3) mf = 3;
    if (u < excl + c2) mf = 2;
    if (u < excl + c1) mf = 1;
    if (u < excl + c0) mf = 0;
    unsigned long long ball = __ballot(mf < 4);
    int item = 0;
    if (ball != 0ULL) {
      int fl = __ffsll(ball) - 1;
      int fj = __shfl(mf, fl);
      item = fl * 4 + fj;
    }
    if (lane == 0) subs[item] = 1.0f;
    float dot[4] = {0.f, 0.f, 0.f, 0.f};
    int tl = (t < 148) ? t : 148;
    int c4 = tl & ~3;
    for (int c = 0; c < c4; c += 4) {
      float4 mb = *(const float4*)&M[item * 148 + c];
#pragma unroll
      for (int g = 0; g < 4; ++g) {
        float4 mr = *(const float4*)&M[(lane + 64 * g) * 148 + c];
        dot[g] += mr.x * mb.x + mr.y * mb.y + mr.z * mb.z + mr.w * mb.w;
      }
    }
    for (int c = c4; c < tl; ++c) {
      float mb = M[item * 148 + c];
#pragma unroll
      for (int g = 0; g < 4; ++g) dot[g] += M[(lane + 64 * g) * 148 + c] * mb;
    }
    for (int c = 148; c < t; ++c) {
      float mb = MG[(c - 148) * 256 + item];
#pragma unroll
      for (int g = 0; g < 4; ++g) dot[g] += MG[(c - 148) * 256 + lane + 64 * g] * mb;
    }
    float pit = p[item];
    float rs = 1.0f / sqrtf(fmaxf(pit, 1e-30f));
#pragma unroll
    for (int g = 0; g < 4; ++g) {
      int r = lane + 64 * g;
      float mn = (P[(size_t)item * 256 + r] - dot[g]) * rs;
      float pn = p[r] - mn * mn;
      p[r] = fmaxf(pn, 0.0f);
      if (t < 148) M[r * 148 + t] = mn;
      else MG[(t - 148) * 256 + r] = mn;
    }
    __syncthreads();
  }
  __syncthreads();
  for (int r = lane; r < 256; r += 64) subset[r] = allsel ? 1.0f : subs[r];
}

// ---------------------------------------------------------------- tail
__global__ void k_pick(const float* __restrict__ subset, const float* __restrict__ words,
                       float* __restrict__ pick) {
  __shared__ float s[256];
  const int tid = threadIdx.x;
  s[tid] = subset[tid];
  __syncthreads();
  const int c = blockIdx.x * 256 + tid;
  float acc = 0.0f;
  for (int r = 0; r < 256; ++r) acc += s[r] * words[r * 2048 + c];
  pick[c] = acc;
}

__global__ void k_p1(const float* __restrict__ pick, const float* __restrict__ W,
                     const float* __restrict__ b, float* __restrict__ p1) {
  __shared__ float s[2048];
  const int tid = threadIdx.x;
  for (int i = tid; i < 2048; i += 256) s[i] = pick[i];
  __syncthreads();
  const int n = blockIdx.x * 256 + tid;
  float acc = b[n];
  for (int r = 0; r < 2048; ++r) acc += s[r] * W[(size_t)r * 4096 + n];
  p1[n] = fmaxf(acc, 0.0f);
}

__global__ void k_final(const float* __restrict__ p1, const float* __restrict__ w2,
                        const float* __restrict__ b2, float* __restrict__ out) {
  __shared__ float red[4];
  const int tid = threadIdx.x;
  float acc = 0.0f;
  for (int i = tid; i < 4096; i += 256) acc += p1[i] * w2[i];
  for (int m = 32; m; m >>= 1) acc += __shfl_xor(acc, m);
  if ((tid & 63) == 0) red[tid >> 6] = acc;
  __syncthreads();
  if (tid == 0) out[0] = red[0] + red[1] + red[2] + red[3] + b2[0];
}

// ---------------------------------------------------------------- launch
extern "C" void kernel_launch(void* const* d_in, const int* in_sizes, int n_in,
                              void* d_out, int out_size, void* d_ws, size_t ws_size,
                              hipStream_t stream) {
  const float* words = (const float*)d_in[0];
  const float* ctx   = (const float*)d_in[1];
  const float* ew1   = (const float*)d_in[2];
  const float* eb1   = (const float*)d_in[3];
  const float* ew2   = (const float*)d_in[4];
  const float* eb2   = (const float*)d_in[5];
  const float* pw1   = (const float*)d_in[6];
  const float* pb1   = (const float*)d_in[7];
  const float* pw2   = (const float*)d_in[8];
  const float* pb2   = (const float*)d_in[9];
  const float* usel  = (const float*)d_in[10];
  const float* uitem = (const float*)d_in[11];
  (void)in_sizes; (void)n_in; (void)out_size; (void)ws_size;
  char* w = (char*)d_ws;

  f16* xh = (f16*)(w + 0);
  f16* xl = (f16*)(w + (size_t)(2 << 20));
  f16* hh = (f16*)(w + (size_t)(4 << 20));
  f16* hl = (f16*)(w + (size_t)(8 << 20));
  f16* Eh = (f16*)(w + (size_t)(12 << 20));
  f16* El = (f16*)(w + (size_t)(14 << 20));
  size_t o = (size_t)(16 << 20);
  float* Km   = (float*)(w + o); o += 262144;
  float* dda  = (float*)(w + o); o += 1024;
  float* ee   = (float*)(w + o); o += 1024;
  float* tt   = (float*)(w + o); o += 1024;
  float* vals = (float*)(w + o); o += 1024;
  float* keep = (float*)(w + o); o += 1024;
  int*   kcnt = (int*)  (w + o); o += 1024;
  float* refl = (float*)(w + o); o += 262144;
  float* ZZ   = (float*)(w + o); o += 262144;
  float* V    = (float*)(w + o); o += 262144;
  float* P    = (float*)(w + o); o += 262144;
  float4* F   = (float4*)(w + o); o += 1048576;   // 256x256 float4 LU factor stream
  uint32_t* pvm = (uint32_t*)(w + o); o += 8192;  // pivot bitmask 8x256 words
  float* MG   = (float*)(w + o); o += 131072;
  float* subset = (float*)(w + o); o += 1024;
  float* pick = (float*)(w + o); o += 8192;
  float* p1   = (float*)(w + o); o += 16384;

  hipFuncSetAttribute((const void*)k_tridiag, hipFuncAttributeMaxDynamicSharedMemorySize, 140000);
  hipFuncSetAttribute((const void*)k_dpp,     hipFuncAttributeMaxDynamicSharedMemorySize, 156000);

  k_split_x<<<4096, 256, 0, stream>>>(words, ctx, xh, xl);
  k_gemm_split<true ><<<dim3(128, 2), 256, 0, stream>>>(xh, xl, ew1, eb1, hh, hl, 256, 8192, 4096);
  k_gemm_split<false><<<dim3( 64, 2), 256, 0, stream>>>(hh, hl, ew2, eb2, Eh, El, 256, 4096, 8192);
  k_kgemm<<<dim3(4, 4), 256, 0, stream>>>(Eh, El, Km);
  k_tridiag<<<1, 1024, 134736, stream>>>(Km, dda, ee, refl, tt);
  k_bisect<<<1, 256, 0, stream>>>(dda, ee, usel, vals, keep, kcnt);
  k_invit<<<1, 256, 0, stream>>>(dda, ee, vals, F, pvm, ZZ);
  k_backxf<<<64, 256, 0, stream>>>(ZZ, refl, tt, V);
  k_pbuild<<<dim3(4, 4), 256, 0, stream>>>(V, keep, P);
  k_dpp<<<1, 64, 153600, stream>>>(P, kcnt, uitem, MG, subset);
  k_pick<<<8, 256, 0, stream>>>(subset, words, pick);
  k_p1<<<16, 256, 0, stream>>>(pick, pw1, pb1, p1);
  k_final<<<1, 256, 0, stream>>>(p1, pw2, pb2, (float*)d_out);
}